// Round 1
// baseline (892.715 us; speedup 1.0000x reference)
//
#include <hip/hip_runtime.h>
#include <math.h>

#define TT 8192
#define DD 128
#define GB 64
#define GN 128
#define GE 2048
#define NEDGE (GB*GE)   // 131072

// ---- workspace layout (bytes) ----
#define WS_COUNT   0u            // 8192 int (32K)
#define WS_FILL    (32u<<10)     // 8192 int (32K)
#define WS_OFFS    (64u<<10)     // 8193 int (~32K)
#define WS_NORM    (100u<<10)    // 8192 f32 (32K)
#define WS_CSR     (132u<<10)    // 131072 int (512K)
#define WS_W2      (644u<<10)    // 128*128 f32 (64K)
#define WS_B2      (708u<<10)    // 128 f32
#define WS_PM      (709u<<10)    // 2*8192 f32 (64K)
#define WS_PL      (773u<<10)    // 2*8192 f32 (64K)
#define WS_H0      (1u<<20)      // 4MB
#define WS_H1      (5u<<20)      // 4MB
#define WS_M       (9u<<20)      // 4MB
#define WS_OPART   (13u<<20)     // 2*8192*128 f32 (8MB)
#define WS_ATT     (21u<<20)     // 4MB
// total 25MB

__global__ __launch_bounds__(256) void k_zero(int* __restrict__ p, int n) {
  int i = blockIdx.x*256 + threadIdx.x;
  if (i < n) p[i] = 0;
}

__global__ __launch_bounds__(256) void k_count(const int* __restrict__ edges, int* __restrict__ count) {
  int e = blockIdx.x*256 + threadIdx.x;       // 0..131071
  int b = e >> 11;
  int i = e & 2047;
  int dst = edges[b*2*GE + GE + i] + b*GN;
  atomicAdd(&count[dst], 1);
}

__global__ __launch_bounds__(1024) void k_scan(const int* __restrict__ count, int* __restrict__ offs,
                                               float* __restrict__ norm) {
  __shared__ int lds[1024];
  int tid = threadIdx.x;
  int base = tid*8;
  int loc[8]; int tot = 0;
  #pragma unroll
  for (int j=0;j<8;j++){ loc[j]=count[base+j]; tot+=loc[j]; }
  lds[tid]=tot; __syncthreads();
  for (int s=1;s<1024;s<<=1){
    int v = (tid>=s)? lds[tid-s] : 0;
    __syncthreads();
    lds[tid]+=v;
    __syncthreads();
  }
  int ex = lds[tid]-tot;
  #pragma unroll
  for (int j=0;j<8;j++){
    offs[base+j]=ex; ex+=loc[j];
    norm[base+j]=rsqrtf(1.0f+(float)loc[j]);   // deg includes self-loop
  }
  if (tid==1023) offs[TT]=ex;
}

__global__ __launch_bounds__(256) void k_fill(const int* __restrict__ edges, const int* __restrict__ offs,
                                              int* __restrict__ fill, int* __restrict__ csr) {
  int e = blockIdx.x*256+threadIdx.x;
  int b = e>>11, i = e&2047;
  int s = edges[b*2*GE + i] + b*GN;
  int d = edges[b*2*GE + GE + i] + b*GN;
  int pos = offs[d] + atomicAdd(&fill[d],1);
  csr[pos] = s;
}

// C[M,128] = A[M,128] @ W[128,128] (+bias), written at C[row*ldc + cofs + col]
__global__ __launch_bounds__(256) void k_gemm(const float* __restrict__ A, const float* __restrict__ W,
                                              const float* __restrict__ bias, float* __restrict__ C,
                                              int ldc, int cofs) {
  __shared__ float As[32*132];
  __shared__ float Ws[128*132];
  int tid = threadIdx.x;
  int row0 = blockIdx.x*32;
  #pragma unroll
  for (int i=0;i<4;i++){
    int idx = i*256+tid;
    int r = idx>>5, c4 = (idx&31)<<2;
    *(float4*)&As[r*132+c4] = *(const float4*)&A[(row0+r)*DD + c4];
  }
  #pragma unroll
  for (int i=0;i<16;i++){
    int idx = i*256+tid;
    int r = idx>>5, c4 = (idx&31)<<2;
    *(float4*)&Ws[r*132+c4] = *(const float4*)&W[r*DD + c4];
  }
  __syncthreads();
  int rg = tid>>4, cg = tid&15;
  int r0 = rg*2, c0 = cg*8;
  float acc[2][8];
  #pragma unroll
  for (int a=0;a<2;a++)
    #pragma unroll
    for (int b=0;b<8;b++) acc[a][b]=0.f;
  for (int kk=0;kk<128;kk+=4){
    float a0[4], a1[4];
    *(float4*)a0 = *(float4*)&As[r0*132+kk];
    *(float4*)a1 = *(float4*)&As[(r0+1)*132+kk];
    #pragma unroll
    for (int j=0;j<4;j++){
      float w[8];
      *(float4*)&w[0] = *(float4*)&Ws[(kk+j)*132+c0];
      *(float4*)&w[4] = *(float4*)&Ws[(kk+j)*132+c0+4];
      #pragma unroll
      for (int m=0;m<8;m++){
        acc[0][m] += a0[j]*w[m];
        acc[1][m] += a1[j]*w[m];
      }
    }
  }
  #pragma unroll
  for (int a=0;a<2;a++){
    float outv[8];
    #pragma unroll
    for (int m=0;m<8;m++)
      outv[m] = acc[a][m] + (bias ? bias[c0+m] : 0.f);
    float* dst = &C[(size_t)(row0+r0+a)*ldc + cofs + c0];
    *(float4*)&dst[0] = *(float4*)&outv[0];
    *(float4*)&dst[4] = *(float4*)&outv[4];
  }
}

// one wave per node; lane handles channels {lane, lane+64}
__global__ __launch_bounds__(256) void k_gather(const float* __restrict__ m, const float* __restrict__ bias,
                                                const float* __restrict__ norm, const int* __restrict__ offs,
                                                const int* __restrict__ csr, float* __restrict__ hout,
                                                int ldc) {
  int w = threadIdx.x>>6, lane = threadIdx.x&63;
  int t = blockIdx.x*4 + w;
  float nt = norm[t];
  float cs = nt*nt;
  float acc0 = m[t*DD + lane]*cs;
  float acc1 = m[t*DD + 64 + lane]*cs;
  int e0 = offs[t], e1 = offs[t+1];
  for (int e=e0;e<e1;e++){
    int s = csr[e];
    float cf = norm[s]*nt;
    acc0 += m[s*DD + lane]*cf;
    acc1 += m[s*DD + 64 + lane]*cf;
  }
  hout[(size_t)t*ldc + lane]      = tanhf(acc0 + bias[lane]);
  hout[(size_t)t*ldc + 64 + lane] = tanhf(acc1 + bias[64+lane]);
}

// W2 = Wo @ (Wc[:128]+Wc[128:]);  b2 = bo @ (Wc[:128]+Wc[128:]) + bc
__global__ __launch_bounds__(256) void k_w2(const float* __restrict__ Wo, const float* __restrict__ bo,
                                            const float* __restrict__ Wc, const float* __restrict__ bc,
                                            float* __restrict__ W2, float* __restrict__ b2) {
  if (blockIdx.x < 64) {
    int gid = blockIdx.x*256 + threadIdx.x;
    int i = gid>>7, j = gid&127;
    float s = 0.f;
    for (int k2=0;k2<128;k2++)
      s += Wo[i*DD+k2]*(Wc[k2*DD+j] + Wc[(k2+128)*DD+j]);
    W2[i*DD+j] = s;
  } else if (threadIdx.x < 128) {
    int j = threadIdx.x;
    float s = bc[j];
    for (int k2=0;k2<128;k2++)
      s += bo[k2]*(Wc[k2*DD+j] + Wc[(k2+128)*DD+j]);
    b2[j] = s;
  }
}

// flash attention: BQ=64, BK=64, 512 threads, KSPLIT=2, grid = 128*2
__global__ __launch_bounds__(512) void k_flash(const float* __restrict__ q, const float* __restrict__ k,
                                               const float* __restrict__ v, float* __restrict__ Opart,
                                               float* __restrict__ pm, float* __restrict__ pl) {
  __shared__ float qs[64*132];
  __shared__ float ks[64*132];
  __shared__ float vs[64*132];
  __shared__ float ss[64*68];
  __shared__ float row_m[64], row_l[64], row_scale[64];
  int tid = threadIdx.x;
  int qt = blockIdx.x >> 1;
  int sp = blockIdx.x & 1;
  int q0 = qt*64;
  #pragma unroll
  for (int i=0;i<4;i++){
    int idx = i*512+tid;
    int r = idx>>5, c4=(idx&31)<<2;
    *(float4*)&qs[r*132+c4] = *(const float4*)&q[(q0+r)*DD + c4];
  }
  if (tid<64){ row_m[tid] = -1e30f; row_l[tid]=0.f; }
  float o[2][8];
  #pragma unroll
  for (int a=0;a<2;a++)
    #pragma unroll
    for (int b=0;b<8;b++) o[a][b]=0.f;
  int rg = tid>>4, cg = tid&15;   // rows {rg, rg+32}; phase1 cols {cg+16i}; PV cols {cg*8..+7}
  for (int tile=0;tile<64;tile++){
    int kbase = sp*4096 + tile*64;
    __syncthreads();                       // previous PV done before restaging
    #pragma unroll
    for (int i=0;i<4;i++){
      int idx=i*512+tid;
      int r=idx>>5, c4=(idx&31)<<2;
      *(float4*)&ks[r*132+c4] = *(const float4*)&k[(kbase+r)*DD+c4];
      *(float4*)&vs[r*132+c4] = *(const float4*)&v[(kbase+r)*DD+c4];
    }
    __syncthreads();
    // ---- phase 1: S = Q.K^T (64x64) ----
    float sa[2][4];
    #pragma unroll
    for (int a=0;a<2;a++){ sa[a][0]=0.f; sa[a][1]=0.f; sa[a][2]=0.f; sa[a][3]=0.f; }
    #pragma unroll 4
    for (int ch=0;ch<128;ch+=4){
      float a0[4], a1[4];
      *(float4*)a0 = *(float4*)&qs[rg*132+ch];
      *(float4*)a1 = *(float4*)&qs[(rg+32)*132+ch];
      #pragma unroll
      for (int i=0;i<4;i++){
        float bb[4];
        *(float4*)bb = *(float4*)&ks[(cg+16*i)*132+ch];
        sa[0][i] += a0[0]*bb[0]+a0[1]*bb[1]+a0[2]*bb[2]+a0[3]*bb[3];
        sa[1][i] += a1[0]*bb[0]+a1[1]*bb[1]+a1[2]*bb[2]+a1[3]*bb[3];
      }
    }
    #pragma unroll
    for (int i=0;i<4;i++){
      ss[rg*68 + cg+16*i]      = sa[0][i];
      ss[(rg+32)*68 + cg+16*i] = sa[1][i];
    }
    __syncthreads();
    // ---- online softmax (8 threads/row, 8 cols each) ----
    {
      int row = tid>>3, i8 = tid&7;
      float p[8];
      *(float4*)&p[0] = *(float4*)&ss[row*68 + i8*8];
      *(float4*)&p[4] = *(float4*)&ss[row*68 + i8*8 + 4];
      float tmax = p[0];
      #pragma unroll
      for (int j=1;j<8;j++) tmax = fmaxf(tmax, p[j]);
      #pragma unroll
      for (int off2=1; off2<8; off2<<=1) tmax = fmaxf(tmax, __shfl_xor(tmax, off2));
      float mold = row_m[row];
      float mnew = fmaxf(mold, tmax);
      float psum = 0.f;
      #pragma unroll
      for (int j=0;j<8;j++){ p[j] = __expf(p[j]-mnew); psum += p[j]; }
      *(float4*)&ss[row*68+i8*8]   = *(float4*)&p[0];
      *(float4*)&ss[row*68+i8*8+4] = *(float4*)&p[4];
      #pragma unroll
      for (int off2=1;off2<8;off2<<=1) psum += __shfl_xor(psum, off2);
      if (i8==0){
        float sc = __expf(mold-mnew);
        row_scale[row]=sc;
        row_l[row] = row_l[row]*sc + psum;
        row_m[row] = mnew;
      }
    }
    __syncthreads();
    // ---- PV: O += P.V ----
    {
      float sc0 = row_scale[rg], sc1 = row_scale[rg+32];
      #pragma unroll
      for (int mm=0;mm<8;mm++){ o[0][mm]*=sc0; o[1][mm]*=sc1; }
      #pragma unroll 4
      for (int kk=0;kk<64;kk++){
        float pa = ss[rg*68+kk];
        float pb = ss[(rg+32)*68+kk];
        float vv[8];
        *(float4*)&vv[0] = *(float4*)&vs[kk*132+cg*8];
        *(float4*)&vv[4] = *(float4*)&vs[kk*132+cg*8+4];
        #pragma unroll
        for (int mm=0;mm<8;mm++){
          o[0][mm] += pa*vv[mm];
          o[1][mm] += pb*vv[mm];
        }
      }
    }
  }
  __syncthreads();
  {
    float* dst0 = &Opart[((size_t)sp*TT + q0 + rg)*DD + cg*8];
    float* dst1 = &Opart[((size_t)sp*TT + q0 + rg+32)*DD + cg*8];
    *(float4*)&dst0[0] = *(float4*)&o[0][0];
    *(float4*)&dst0[4] = *(float4*)&o[0][4];
    *(float4*)&dst1[0] = *(float4*)&o[1][0];
    *(float4*)&dst1[4] = *(float4*)&o[1][4];
    if (tid<64){ pm[sp*TT + q0+tid]=row_m[tid]; pl[sp*TT+q0+tid]=row_l[tid]; }
  }
}

__global__ __launch_bounds__(256) void k_combine(const float* __restrict__ Opart, const float* __restrict__ pm,
                                                 const float* __restrict__ pl, float* __restrict__ att) {
  int t = blockIdx.x*2 + (threadIdx.x>>7);
  int c = threadIdx.x&127;
  float m0 = pm[t], m1 = pm[TT+t];
  float mx = fmaxf(m0,m1);
  float w0 = __expf(m0-mx), w1 = __expf(m1-mx);
  float den = pl[t]*w0 + pl[TT+t]*w1;
  float val = Opart[(size_t)t*DD+c]*w0 + Opart[((size_t)TT+t)*DD+c]*w1;
  att[(size_t)t*DD+c] = val/den;
}

extern "C" void kernel_launch(void* const* d_in, const int* in_sizes, int n_in,
                              void* d_out, int out_size, void* d_ws, size_t ws_size,
                              hipStream_t stream) {
  const float* x  = (const float*)d_in[0];
  const int* edges = (const int*)d_in[1];
  const float* Wg = (const float*)d_in[2];
  const float* bg = (const float*)d_in[3];
  const float* Wq = (const float*)d_in[4];
  const float* bq = (const float*)d_in[5];
  const float* Wk = (const float*)d_in[6];
  const float* bk = (const float*)d_in[7];
  const float* Wv = (const float*)d_in[8];
  const float* bv = (const float*)d_in[9];
  const float* Wo = (const float*)d_in[10];
  const float* bo = (const float*)d_in[11];
  const float* Wc = (const float*)d_in[12];
  const float* bc = (const float*)d_in[13];
  float* out = (float*)d_out;
  char* ws = (char*)d_ws;

  int* count = (int*)(ws + WS_COUNT);
  int* fill  = (int*)(ws + WS_FILL);
  int* offs  = (int*)(ws + WS_OFFS);
  float* norm = (float*)(ws + WS_NORM);
  int* csr   = (int*)(ws + WS_CSR);
  float* W2  = (float*)(ws + WS_W2);
  float* b2  = (float*)(ws + WS_B2);
  float* pm  = (float*)(ws + WS_PM);
  float* pl  = (float*)(ws + WS_PL);
  float* h0  = (float*)(ws + WS_H0);
  float* h1  = (float*)(ws + WS_H1);
  float* mbuf = (float*)(ws + WS_M);
  float* Opart = (float*)(ws + WS_OPART);
  float* att = (float*)(ws + WS_ATT);

  // CSR build
  k_zero<<<64,256,0,stream>>>(count, 16384);           // count + fill (contiguous)
  k_count<<<NEDGE/256,256,0,stream>>>(edges, count);
  k_scan<<<1,1024,0,stream>>>(count, offs, norm);
  k_fill<<<NEDGE/256,256,0,stream>>>(edges, offs, fill, csr);

  // GCN: x -> h0 -> h1 -> h0 -> out[:, :128]
  const float* cur = x;
  float* hb[2] = {h0, h1};
  for (int l=0; l<4; ++l) {
    k_gemm<<<256,256,0,stream>>>(cur, Wg + l*DD*DD, nullptr, mbuf, DD, 0);
    float* nxt; int ldc;
    if (l < 3) { nxt = hb[l&1]; ldc = DD; } else { nxt = out; ldc = 2*DD; }
    k_gather<<<TT/4,256,0,stream>>>(mbuf, bg + l*DD, norm, offs, csr, nxt, ldc);
    cur = nxt;
  }

  // attention on original x (reuse h0/h1/mbuf as q/k/v)
  float* qb = h0; float* kb = h1; float* vb = mbuf;
  k_gemm<<<256,256,0,stream>>>(x, Wq, bq, qb, DD, 0);
  k_gemm<<<256,256,0,stream>>>(x, Wk, bk, kb, DD, 0);
  k_gemm<<<256,256,0,stream>>>(x, Wv, bv, vb, DD, 0);
  k_w2<<<65,256,0,stream>>>(Wo, bo, Wc, bc, W2, b2);
  k_flash<<<256,512,0,stream>>>(qb, kb, vb, Opart, pm, pl);
  k_combine<<<TT/2,256,0,stream>>>(Opart, pm, pl, att);
  k_gemm<<<256,256,0,stream>>>(att, W2, b2, out, 2*DD, DD);
}

// Round 2
// 338.449 us; speedup vs baseline: 2.6377x; 2.6377x over previous
//
#include <hip/hip_runtime.h>
#include <math.h>

#define TT 8192
#define DD 128
#define GB 64
#define GN 128
#define GE 2048
#define NEDGE (GB*GE)   // 131072

// ---- workspace layout (bytes) ----
#define WS_COUNT   0u            // 8192 int
#define WS_FILL    (32u<<10)     // 8192 int
#define WS_OFFS    (64u<<10)     // 8193 int
#define WS_NORM    (100u<<10)    // 8192 f32
#define WS_CSR     (132u<<10)    // 131072 int
#define WS_W2      (644u<<10)    // 128*128 f32
#define WS_B2      (708u<<10)    // 128 f32
#define WS_PM      (709u<<10)    // 2*8192 f32
#define WS_PL      (773u<<10)    // 2*8192 f32
#define WS_H0      (1u<<20)      // 4MB region: qh(2MB) + ql(2MB) after GCN
#define WS_H1      (5u<<20)      // 4MB region: kh(2MB) + kl(2MB)
#define WS_M       (9u<<20)      // 4MB region: GCN mbuf, then vT(2MB)
#define WS_OPART   (13u<<20)     // 8MB
#define WS_ATT     (21u<<20)     // 4MB
// total 25MB

typedef short  bfrag  __attribute__((ext_vector_type(8)));
typedef short  bfrag4 __attribute__((ext_vector_type(4)));
typedef float  ffrag  __attribute__((ext_vector_type(4)));
typedef unsigned short u16x8 __attribute__((ext_vector_type(8)));

#define MFMA(a,b,c) __builtin_amdgcn_mfma_f32_16x16x32_bf16((a),(b),(c),0,0,0)

typedef __attribute__((address_space(1))) unsigned int gu32_t;
typedef __attribute__((address_space(3))) unsigned int lu32_t;
#define GLOAD16(gp, lp) __builtin_amdgcn_global_load_lds((gu32_t*)(const void*)(gp), (lu32_t*)(void*)(lp), 16, 0, 0)

__device__ __forceinline__ float bf2f(unsigned short u){
  unsigned v = ((unsigned)u)<<16; return __builtin_bit_cast(float, v);
}
__device__ __forceinline__ unsigned short f2bf(float f){
  unsigned u = __builtin_bit_cast(unsigned, f);
  u += 0x7FFFu + ((u>>16)&1u);
  return (unsigned short)(u>>16);
}

__global__ __launch_bounds__(256) void k_zero(int* __restrict__ p, int n) {
  int i = blockIdx.x*256 + threadIdx.x;
  if (i < n) p[i] = 0;
}

__global__ __launch_bounds__(256) void k_count(const int* __restrict__ edges, int* __restrict__ count) {
  int e = blockIdx.x*256 + threadIdx.x;
  int b = e >> 11;
  int i = e & 2047;
  int dst = edges[b*2*GE + GE + i] + b*GN;
  atomicAdd(&count[dst], 1);
}

__global__ __launch_bounds__(1024) void k_scan(const int* __restrict__ count, int* __restrict__ offs,
                                               float* __restrict__ norm) {
  __shared__ int lds[1024];
  int tid = threadIdx.x;
  int base = tid*8;
  int loc[8]; int tot = 0;
  #pragma unroll
  for (int j=0;j<8;j++){ loc[j]=count[base+j]; tot+=loc[j]; }
  lds[tid]=tot; __syncthreads();
  for (int s=1;s<1024;s<<=1){
    int v = (tid>=s)? lds[tid-s] : 0;
    __syncthreads();
    lds[tid]+=v;
    __syncthreads();
  }
  int ex = lds[tid]-tot;
  #pragma unroll
  for (int j=0;j<8;j++){
    offs[base+j]=ex; ex+=loc[j];
    norm[base+j]=rsqrtf(1.0f+(float)loc[j]);
  }
  if (tid==1023) offs[TT]=ex;
}

__global__ __launch_bounds__(256) void k_fill(const int* __restrict__ edges, const int* __restrict__ offs,
                                              int* __restrict__ fill, int* __restrict__ csr) {
  int e = blockIdx.x*256+threadIdx.x;
  int b = e>>11, i = e&2047;
  int s = edges[b*2*GE + i] + b*GN;
  int d = edges[b*2*GE + GE + i] + b*GN;
  int pos = offs[d] + atomicAdd(&fill[d],1);
  csr[pos] = s;
}

// C[M,128] = A[M,128] @ W[128,128] (+bias), written at C[row*ldc + cofs + col]
__global__ __launch_bounds__(256) void k_gemm(const float* __restrict__ A, const float* __restrict__ W,
                                              const float* __restrict__ bias, float* __restrict__ C,
                                              int ldc, int cofs) {
  __shared__ float As[32*132];
  __shared__ float Ws[128*132];
  int tid = threadIdx.x;
  int row0 = blockIdx.x*32;
  #pragma unroll
  for (int i=0;i<4;i++){
    int idx = i*256+tid;
    int r = idx>>5, c4 = (idx&31)<<2;
    *(float4*)&As[r*132+c4] = *(const float4*)&A[(row0+r)*DD + c4];
  }
  #pragma unroll
  for (int i=0;i<16;i++){
    int idx = i*256+tid;
    int r = idx>>5, c4 = (idx&31)<<2;
    *(float4*)&Ws[r*132+c4] = *(const float4*)&W[r*DD + c4];
  }
  __syncthreads();
  int rg = tid>>4, cg = tid&15;
  int r0 = rg*2, c0 = cg*8;
  float acc[2][8];
  #pragma unroll
  for (int a=0;a<2;a++)
    #pragma unroll
    for (int b=0;b<8;b++) acc[a][b]=0.f;
  for (int kk=0;kk<128;kk+=4){
    float a0[4], a1[4];
    *(float4*)a0 = *(float4*)&As[r0*132+kk];
    *(float4*)a1 = *(float4*)&As[(r0+1)*132+kk];
    #pragma unroll
    for (int j=0;j<4;j++){
      float w[8];
      *(float4*)&w[0] = *(float4*)&Ws[(kk+j)*132+c0];
      *(float4*)&w[4] = *(float4*)&Ws[(kk+j)*132+c0+4];
      #pragma unroll
      for (int m=0;m<8;m++){
        acc[0][m] += a0[j]*w[m];
        acc[1][m] += a1[j]*w[m];
      }
    }
  }
  #pragma unroll
  for (int a=0;a<2;a++){
    float outv[8];
    #pragma unroll
    for (int m=0;m<8;m++)
      outv[m] = acc[a][m] + (bias ? bias[c0+m] : 0.f);
    float* dst = &C[(size_t)(row0+r0+a)*ldc + cofs + c0];
    *(float4*)&dst[0] = *(float4*)&outv[0];
    *(float4*)&dst[4] = *(float4*)&outv[4];
  }
}

// projection GEMM with bf16 epilogues.
// mode 0 (Q): o1 = bf16_hi(val) [row][col], o2 = bf16_lo residual
// mode 1 (K): same but cols stored at d ^ ((row&7)<<3)  (LDS-read swizzle baked in)
// mode 2 (V): o1[d][row ^ ((d&15)<<2)] = bf16(val)      (transposed + granule swizzle)
__global__ __launch_bounds__(256) void k_proj(const float* __restrict__ A, const float* __restrict__ W,
                                              const float* __restrict__ bias,
                                              unsigned short* __restrict__ o1,
                                              unsigned short* __restrict__ o2, int mode) {
  __shared__ float As[32*132];
  __shared__ float Ws[128*132];
  int tid = threadIdx.x;
  int row0 = blockIdx.x*32;
  #pragma unroll
  for (int i=0;i<4;i++){
    int idx = i*256+tid;
    int r = idx>>5, c4 = (idx&31)<<2;
    *(float4*)&As[r*132+c4] = *(const float4*)&A[(row0+r)*DD + c4];
  }
  #pragma unroll
  for (int i=0;i<16;i++){
    int idx = i*256+tid;
    int r = idx>>5, c4 = (idx&31)<<2;
    *(float4*)&Ws[r*132+c4] = *(const float4*)&W[r*DD + c4];
  }
  __syncthreads();
  int rg = tid>>4, cg = tid&15;
  int r0 = rg*2, c0 = cg*8;
  float acc[2][8];
  #pragma unroll
  for (int a=0;a<2;a++)
    #pragma unroll
    for (int b=0;b<8;b++) acc[a][b]=0.f;
  for (int kk=0;kk<128;kk+=4){
    float a0[4], a1[4];
    *(float4*)a0 = *(float4*)&As[r0*132+kk];
    *(float4*)a1 = *(float4*)&As[(r0+1)*132+kk];
    #pragma unroll
    for (int j=0;j<4;j++){
      float w[8];
      *(float4*)&w[0] = *(float4*)&Ws[(kk+j)*132+c0];
      *(float4*)&w[4] = *(float4*)&Ws[(kk+j)*132+c0+4];
      #pragma unroll
      for (int m=0;m<8;m++){
        acc[0][m] += a0[j]*w[m];
        acc[1][m] += a1[j]*w[m];
      }
    }
  }
  #pragma unroll
  for (int a=0;a<2;a++){
    int row = row0 + r0 + a;
    float val[8];
    #pragma unroll
    for (int m=0;m<8;m++) val[m] = acc[a][m] + bias[c0+m];
    if (mode == 2) {
      #pragma unroll
      for (int m=0;m<8;m++){
        int d = c0 + m;
        o1[(size_t)d*TT + (row ^ ((d&15)<<2))] = f2bf(val[m]);
      }
    } else {
      unsigned short h8[8], l8[8];
      #pragma unroll
      for (int m=0;m<8;m++){
        unsigned short hb = f2bf(val[m]);
        h8[m] = hb;
        l8[m] = f2bf(val[m] - bf2f(hb));
      }
      int dc = (mode == 1) ? 8*(cg ^ (row&7)) : c0;
      *(u16x8*)&o1[(size_t)row*DD + dc] = *(const u16x8*)h8;
      *(u16x8*)&o2[(size_t)row*DD + dc] = *(const u16x8*)l8;
    }
  }
}

// one wave per node; lane handles channels {lane, lane+64}
__global__ __launch_bounds__(256) void k_gather(const float* __restrict__ m, const float* __restrict__ bias,
                                                const float* __restrict__ norm, const int* __restrict__ offs,
                                                const int* __restrict__ csr, float* __restrict__ hout,
                                                int ldc) {
  int w = threadIdx.x>>6, lane = threadIdx.x&63;
  int t = blockIdx.x*4 + w;
  float nt = norm[t];
  float cs = nt*nt;
  float acc0 = m[t*DD + lane]*cs;
  float acc1 = m[t*DD + 64 + lane]*cs;
  int e0 = offs[t], e1 = offs[t+1];
  for (int e=e0;e<e1;e++){
    int s = csr[e];
    float cf = norm[s]*nt;
    acc0 += m[s*DD + lane]*cf;
    acc1 += m[s*DD + 64 + lane]*cf;
  }
  hout[(size_t)t*ldc + lane]      = tanhf(acc0 + bias[lane]);
  hout[(size_t)t*ldc + 64 + lane] = tanhf(acc1 + bias[64+lane]);
}

// W2 = Wo @ (Wc[:128]+Wc[128:]);  b2 = bo @ (Wc[:128]+Wc[128:]) + bc
__global__ __launch_bounds__(256) void k_w2(const float* __restrict__ Wo, const float* __restrict__ bo,
                                            const float* __restrict__ Wc, const float* __restrict__ bc,
                                            float* __restrict__ W2, float* __restrict__ b2) {
  if (blockIdx.x < 64) {
    int gid = blockIdx.x*256 + threadIdx.x;
    int i = gid>>7, j = gid&127;
    float s = 0.f;
    for (int k2=0;k2<128;k2++)
      s += Wo[i*DD+k2]*(Wc[k2*DD+j] + Wc[(k2+128)*DD+j]);
    W2[i*DD+j] = s;
  } else if (threadIdx.x < 128) {
    int j = threadIdx.x;
    float s = bc[j];
    for (int k2=0;k2<128;k2++)
      s += bo[k2]*(Wc[k2*DD+j] + Wc[(k2+128)*DD+j]);
    b2[j] = s;
  }
}

// MFMA flash attention. 256 threads = 4 waves; BQ=64 (16 q-cols/wave), BK=64, KSPLIT=2.
// S^T = K*Q^T via mfma_16x16x32_bf16 with 3-term hi/lo split (fp32-accurate scores).
// Softmax lane-local (16 vals) + 2 shfl_xor. P stays in registers: its S^T D-frag
// slots {k=16mt+4g+r} are exactly the PV A-frag slots under the k-permutation that
// the granule-swizzled V^T reads implement on the B side.
__global__ __launch_bounds__(256) void k_flash_mfma(
    const unsigned short* __restrict__ qhg, const unsigned short* __restrict__ qlg,
    const unsigned short* __restrict__ khg, const unsigned short* __restrict__ klg,
    const unsigned short* __restrict__ vTg,
    float* __restrict__ Opart, float* __restrict__ pm, float* __restrict__ pl)
{
  __shared__ alignas(16) unsigned short Khs[64*128];
  __shared__ alignas(16) unsigned short Kls[64*128];
  __shared__ alignas(16) unsigned short Vts[128*64];
  const int tid  = threadIdx.x;
  const int lane = tid & 63;
  const int w    = tid >> 6;
  const int l15  = lane & 15;
  const int g    = lane >> 4;
  const int qt   = blockIdx.x >> 1;
  const int sp   = blockIdx.x & 1;
  const int q0   = qt*64;

  // Q B-frags (hi/lo), 4 d-steps, held in registers for the whole kernel
  bfrag qfh[4], qfl[4];
  {
    const unsigned short* qr  = qhg + (size_t)(q0 + 16*w + l15)*DD + 8*g;
    const unsigned short* qr2 = qlg + (size_t)(q0 + 16*w + l15)*DD + 8*g;
    #pragma unroll
    for (int ds=0; ds<4; ++ds){
      qfh[ds] = *(const bfrag*)(qr  + 32*ds);
      qfl[ds] = *(const bfrag*)(qr2 + 32*ds);
    }
  }
  float mrun = -1e30f, lrun = 0.f;
  ffrag o[8];
  #pragma unroll
  for (int nt=0;nt<8;++nt) o[nt] = (ffrag){0.f,0.f,0.f,0.f};

  for (int tile=0; tile<64; ++tile){
    const int kbase = sp*4096 + tile*64;
    __syncthreads();                       // previous tile's LDS reads done
    #pragma unroll
    for (int i=0;i<4;++i){
      const int ii = 4*w + i;
      const int L  = 512*ii + lane*8;
      GLOAD16(khg + (size_t)kbase*DD + L, &Khs[512*ii]);
      GLOAD16(klg + (size_t)kbase*DD + L, &Kls[512*ii]);
      GLOAD16(vTg + (size_t)(L>>6)*TT + kbase + (L&63), &Vts[512*ii]);
    }
    __syncthreads();                       // staging complete (vmcnt drained)

    // ---- S^T = K . Q^T, 3-term split ----
    ffrag s[4];
    #pragma unroll
    for (int mt=0;mt<4;++mt) s[mt] = (ffrag){0.f,0.f,0.f,0.f};
    #pragma unroll
    for (int ds=0; ds<4; ++ds){
      const int koff = (32*ds + 8*g) ^ ((l15&7)<<3);
      #pragma unroll
      for (int mt=0; mt<4; ++mt){
        const int rb = (16*mt + l15)*DD + koff;
        bfrag ka = *(const bfrag*)&Khs[rb];
        bfrag kb = *(const bfrag*)&Kls[rb];
        s[mt] = MFMA(ka, qfh[ds], s[mt]);
        s[mt] = MFMA(kb, qfh[ds], s[mt]);
        s[mt] = MFMA(ka, qfl[ds], s[mt]);
      }
    }

    // ---- online softmax: lane holds 16 of 64 k-values for q-col (l15+16w) ----
    float tmax = -1e30f;
    #pragma unroll
    for (int mt=0;mt<4;++mt)
      #pragma unroll
      for (int r=0;r<4;++r) tmax = fmaxf(tmax, s[mt][r]);
    tmax = fmaxf(tmax, __shfl_xor(tmax, 16));
    tmax = fmaxf(tmax, __shfl_xor(tmax, 32));
    const float mnew  = fmaxf(mrun, tmax);
    const float scale = __expf(mrun - mnew);
    float p[4][4];
    float psum = 0.f;
    #pragma unroll
    for (int mt=0;mt<4;++mt)
      #pragma unroll
      for (int r=0;r<4;++r){ float e = __expf(s[mt][r]-mnew); p[mt][r]=e; psum += e; }
    psum += __shfl_xor(psum, 16);
    psum += __shfl_xor(psum, 32);
    lrun = lrun*scale + psum;
    mrun = mnew;

    // rescale O (rows q = 4g+r need scale from lane 4g+r)
    #pragma unroll
    for (int r=0;r<4;++r){
      const float sc = __shfl(scale, 4*g + r);
      #pragma unroll
      for (int nt=0;nt<8;++nt) o[nt][r] *= sc;
    }

    // ---- PV: O += P.V  (P from registers; V via swizzled V^T reads) ----
    #pragma unroll
    for (int s2=0;s2<2;++s2){
      bfrag pf;
      pf[0]=(short)f2bf(p[2*s2][0]);   pf[1]=(short)f2bf(p[2*s2][1]);
      pf[2]=(short)f2bf(p[2*s2][2]);   pf[3]=(short)f2bf(p[2*s2][3]);
      pf[4]=(short)f2bf(p[2*s2+1][0]); pf[5]=(short)f2bf(p[2*s2+1][1]);
      pf[6]=(short)f2bf(p[2*s2+1][2]); pf[7]=(short)f2bf(p[2*s2+1][3]);
      const int gr0 = (8*s2 + g)     ^ l15;
      const int gr1 = (8*s2 + 4 + g) ^ l15;
      #pragma unroll
      for (int nt=0;nt<8;++nt){
        const unsigned short* vrow = &Vts[(16*nt + l15)*64];
        bfrag4 va = *(const bfrag4*)(vrow + 4*gr0);
        bfrag4 vb = *(const bfrag4*)(vrow + 4*gr1);
        bfrag vf = __builtin_shufflevector(va, vb, 0,1,2,3,4,5,6,7);
        o[nt] = MFMA(pf, vf, o[nt]);
      }
    }
  }

  // ---- epilogue: unnormalized O + (m,l) per q ----
  #pragma unroll
  for (int r=0;r<4;++r){
    float* dst = &Opart[((size_t)sp*TT + q0 + 16*w + 4*g + r)*DD + l15];
    #pragma unroll
    for (int nt=0;nt<8;++nt) dst[16*nt] = o[nt][r];
  }
  if (g==0){
    pm[sp*TT + q0 + 16*w + l15] = mrun;
    pl[sp*TT + q0 + 16*w + l15] = lrun;
  }
}

__global__ __launch_bounds__(256) void k_combine(const float* __restrict__ Opart, const float* __restrict__ pm,
                                                 const float* __restrict__ pl, float* __restrict__ att) {
  int t = blockIdx.x*2 + (threadIdx.x>>7);
  int c = threadIdx.x&127;
  float m0 = pm[t], m1 = pm[TT+t];
  float mx = fmaxf(m0,m1);
  float w0 = __expf(m0-mx), w1 = __expf(m1-mx);
  float den = pl[t]*w0 + pl[TT+t]*w1;
  float val = Opart[(size_t)t*DD+c]*w0 + Opart[((size_t)TT+t)*DD+c]*w1;
  att[(size_t)t*DD+c] = val/den;
}

extern "C" void kernel_launch(void* const* d_in, const int* in_sizes, int n_in,
                              void* d_out, int out_size, void* d_ws, size_t ws_size,
                              hipStream_t stream) {
  const float* x  = (const float*)d_in[0];
  const int* edges = (const int*)d_in[1];
  const float* Wg = (const float*)d_in[2];
  const float* bg = (const float*)d_in[3];
  const float* Wq = (const float*)d_in[4];
  const float* bq = (const float*)d_in[5];
  const float* Wk = (const float*)d_in[6];
  const float* bk = (const float*)d_in[7];
  const float* Wv = (const float*)d_in[8];
  const float* bv = (const float*)d_in[9];
  const float* Wo = (const float*)d_in[10];
  const float* bo = (const float*)d_in[11];
  const float* Wc = (const float*)d_in[12];
  const float* bc = (const float*)d_in[13];
  float* out = (float*)d_out;
  char* ws = (char*)d_ws;

  int* count = (int*)(ws + WS_COUNT);
  int* fill  = (int*)(ws + WS_FILL);
  int* offs  = (int*)(ws + WS_OFFS);
  float* norm = (float*)(ws + WS_NORM);
  int* csr   = (int*)(ws + WS_CSR);
  float* W2  = (float*)(ws + WS_W2);
  float* b2  = (float*)(ws + WS_B2);
  float* pm  = (float*)(ws + WS_PM);
  float* pl  = (float*)(ws + WS_PL);
  float* h0  = (float*)(ws + WS_H0);
  float* h1  = (float*)(ws + WS_H1);
  float* mbuf = (float*)(ws + WS_M);
  float* Opart = (float*)(ws + WS_OPART);
  float* att = (float*)(ws + WS_ATT);
  // bf16 buffers reuse the GCN scratch (GCN finishes before projections run)
  unsigned short* qhb = (unsigned short*)(ws + WS_H0);
  unsigned short* qlb = (unsigned short*)(ws + WS_H0 + (2u<<20));
  unsigned short* khb = (unsigned short*)(ws + WS_H1);
  unsigned short* klb = (unsigned short*)(ws + WS_H1 + (2u<<20));
  unsigned short* vTb = (unsigned short*)(ws + WS_M);

  // CSR build
  k_zero<<<64,256,0,stream>>>(count, 16384);
  k_count<<<NEDGE/256,256,0,stream>>>(edges, count);
  k_scan<<<1,1024,0,stream>>>(count, offs, norm);
  k_fill<<<NEDGE/256,256,0,stream>>>(edges, offs, fill, csr);

  // GCN: x -> h0 -> h1 -> h0 -> out[:, :128]
  const float* cur = x;
  float* hb[2] = {h0, h1};
  for (int l=0; l<4; ++l) {
    k_gemm<<<256,256,0,stream>>>(cur, Wg + l*DD*DD, nullptr, mbuf, DD, 0);
    float* nxt; int ldc;
    if (l < 3) { nxt = hb[l&1]; ldc = DD; } else { nxt = out; ldc = 2*DD; }
    k_gather<<<TT/4,256,0,stream>>>(mbuf, bg + l*DD, norm, offs, csr, nxt, ldc);
    cur = nxt;
  }

  // projections (bf16 hi/lo for Q,K; swizzled transposed bf16 for V)
  k_proj<<<256,256,0,stream>>>(x, Wq, bq, qhb, qlb, 0);
  k_proj<<<256,256,0,stream>>>(x, Wk, bk, khb, klb, 1);
  k_proj<<<256,256,0,stream>>>(x, Wv, bv, vTb, nullptr, 2);
  k_w2<<<65,256,0,stream>>>(Wo, bo, Wc, bc, W2, b2);

  k_flash_mfma<<<256,256,0,stream>>>(qhb, qlb, khb, klb, vTb, Opart, pm, pl);
  k_combine<<<TT/2,256,0,stream>>>(Opart, pm, pl, att);
  k_gemm<<<256,256,0,stream>>>(att, W2, b2, out, 2*DD, DD);
}

// Round 3
// 297.564 us; speedup vs baseline: 3.0001x; 1.1374x over previous
//
#include <hip/hip_runtime.h>
#include <math.h>

#define TT 8192
#define DD 128
#define GB 64
#define GN 128
#define GE 2048
#define NEDGE (GB*GE)   // 131072

// ---- workspace layout (bytes) ----
#define WS_COUNT   0u            // 8192 int
#define WS_FILL    (32u<<10)     // 8192 int
#define WS_OFFS    (64u<<10)     // 8193 int
#define WS_NORM    (100u<<10)    // 8192 f32
#define WS_CSR     (132u<<10)    // 131072 int
#define WS_W2      (644u<<10)    // 128*128 f32
#define WS_B2      (708u<<10)    // 128 f32
#define WS_PM      (709u<<10)    // 2*8192 f32
#define WS_PL      (773u<<10)    // 2*8192 f32
#define WS_H0      (1u<<20)      // 4MB region: qh(2MB) + ql(2MB) after GCN
#define WS_H1      (5u<<20)      // 4MB region: kh(2MB) + kl(2MB)
#define WS_M       (9u<<20)      // 4MB region: GCN mbuf, then vT(2MB)
#define WS_OPART   (13u<<20)     // 8MB
// total 21MB

typedef short  bfrag  __attribute__((ext_vector_type(8)));
typedef short  bfrag4 __attribute__((ext_vector_type(4)));
typedef float  ffrag  __attribute__((ext_vector_type(4)));
typedef unsigned short u16x8 __attribute__((ext_vector_type(8)));

#define MFMA(a,b,c) __builtin_amdgcn_mfma_f32_16x16x32_bf16((a),(b),(c),0,0,0)

typedef __attribute__((address_space(1))) unsigned int gu32_t;
typedef __attribute__((address_space(3))) unsigned int lu32_t;
#define GLOAD16(gp, lp) __builtin_amdgcn_global_load_lds((gu32_t*)(const void*)(gp), (lu32_t*)(void*)(lp), 16, 0, 0)

__device__ __forceinline__ float bf2f(unsigned short u){
  unsigned v = ((unsigned)u)<<16; return __builtin_bit_cast(float, v);
}
__device__ __forceinline__ unsigned short f2bf(float f){
  unsigned u = __builtin_bit_cast(unsigned, f);
  u += 0x7FFFu + ((u>>16)&1u);
  return (unsigned short)(u>>16);
}

__global__ __launch_bounds__(256) void k_zero(int* __restrict__ p, int n) {
  int i = blockIdx.x*256 + threadIdx.x;
  if (i < n) p[i] = 0;
}

__global__ __launch_bounds__(256) void k_count(const int* __restrict__ edges, int* __restrict__ count) {
  int e = blockIdx.x*256 + threadIdx.x;
  int b = e >> 11;
  int i = e & 2047;
  int dst = edges[b*2*GE + GE + i] + b*GN;
  atomicAdd(&count[dst], 1);
}

__global__ __launch_bounds__(1024) void k_scan(const int* __restrict__ count, int* __restrict__ offs,
                                               float* __restrict__ norm) {
  __shared__ int lds[1024];
  int tid = threadIdx.x;
  int base = tid*8;
  int loc[8]; int tot = 0;
  #pragma unroll
  for (int j=0;j<8;j++){ loc[j]=count[base+j]; tot+=loc[j]; }
  lds[tid]=tot; __syncthreads();
  for (int s=1;s<1024;s<<=1){
    int v = (tid>=s)? lds[tid-s] : 0;
    __syncthreads();
    lds[tid]+=v;
    __syncthreads();
  }
  int ex = lds[tid]-tot;
  #pragma unroll
  for (int j=0;j<8;j++){
    offs[base+j]=ex; ex+=loc[j];
    norm[base+j]=rsqrtf(1.0f+(float)loc[j]);
  }
  if (tid==1023) offs[TT]=ex;
}

__global__ __launch_bounds__(256) void k_fill(const int* __restrict__ edges, const int* __restrict__ offs,
                                              int* __restrict__ fill, int* __restrict__ csr) {
  int e = blockIdx.x*256+threadIdx.x;
  int b = e>>11, i = e&2047;
  int s = edges[b*2*GE + i] + b*GN;
  int d = edges[b*2*GE + GE + i] + b*GN;
  int pos = offs[d] + atomicAdd(&fill[d],1);
  csr[pos] = s;
}

// C[M,128] = A[M,128] @ W[128,128] (+bias), written at C[row*ldc + cofs + col]
__global__ __launch_bounds__(256) void k_gemm(const float* __restrict__ A, const float* __restrict__ W,
                                              const float* __restrict__ bias, float* __restrict__ C,
                                              int ldc, int cofs) {
  __shared__ float As[32*132];
  __shared__ float Ws[128*132];
  int tid = threadIdx.x;
  int row0 = blockIdx.x*32;
  #pragma unroll
  for (int i=0;i<4;i++){
    int idx = i*256+tid;
    int r = idx>>5, c4 = (idx&31)<<2;
    *(float4*)&As[r*132+c4] = *(const float4*)&A[(row0+r)*DD + c4];
  }
  #pragma unroll
  for (int i=0;i<16;i++){
    int idx = i*256+tid;
    int r = idx>>5, c4 = (idx&31)<<2;
    *(float4*)&Ws[r*132+c4] = *(const float4*)&W[r*DD + c4];
  }
  __syncthreads();
  int rg = tid>>4, cg = tid&15;
  int r0 = rg*2, c0 = cg*8;
  float acc[2][8];
  #pragma unroll
  for (int a=0;a<2;a++)
    #pragma unroll
    for (int b=0;b<8;b++) acc[a][b]=0.f;
  for (int kk=0;kk<128;kk+=4){
    float a0[4], a1[4];
    *(float4*)a0 = *(float4*)&As[r0*132+kk];
    *(float4*)a1 = *(float4*)&As[(r0+1)*132+kk];
    #pragma unroll
    for (int j=0;j<4;j++){
      float w[8];
      *(float4*)&w[0] = *(float4*)&Ws[(kk+j)*132+c0];
      *(float4*)&w[4] = *(float4*)&Ws[(kk+j)*132+c0+4];
      #pragma unroll
      for (int m=0;m<8;m++){
        acc[0][m] += a0[j]*w[m];
        acc[1][m] += a1[j]*w[m];
      }
    }
  }
  #pragma unroll
  for (int a=0;a<2;a++){
    float outv[8];
    #pragma unroll
    for (int m=0;m<8;m++)
      outv[m] = acc[a][m] + (bias ? bias[c0+m] : 0.f);
    float* dst = &C[(size_t)(row0+r0+a)*ldc + cofs + c0];
    *(float4*)&dst[0] = *(float4*)&outv[0];
    *(float4*)&dst[4] = *(float4*)&outv[4];
  }
}

// merged Q/K/V projections (one launch, grid 768).
// mode 0 (Q): qh/ql hi-lo bf16 [row][col]
// mode 1 (K): kh/kl hi-lo bf16, cols stored at d ^ ((row&7)<<3)
// mode 2 (V): vT[d][row ^ ((d&7)<<2)] = bf16(val)   (transposed, 32-granule swizzle)
__global__ __launch_bounds__(256) void k_proj3(const float* __restrict__ A,
                                               const float* __restrict__ Wq, const float* __restrict__ bq_,
                                               const float* __restrict__ Wk, const float* __restrict__ bk_,
                                               const float* __restrict__ Wv, const float* __restrict__ bv_,
                                               unsigned short* __restrict__ qh, unsigned short* __restrict__ ql,
                                               unsigned short* __restrict__ kh, unsigned short* __restrict__ kl,
                                               unsigned short* __restrict__ vT) {
  __shared__ float As[32*132];
  __shared__ float Ws[128*132];
  const int mode = blockIdx.x >> 8;
  const int row0 = (blockIdx.x & 255) * 32;
  const float* W    = (mode==0) ? Wq : (mode==1) ? Wk : Wv;
  const float* bias = (mode==0) ? bq_ : (mode==1) ? bk_ : bv_;
  int tid = threadIdx.x;
  #pragma unroll
  for (int i=0;i<4;i++){
    int idx = i*256+tid;
    int r = idx>>5, c4 = (idx&31)<<2;
    *(float4*)&As[r*132+c4] = *(const float4*)&A[(row0+r)*DD + c4];
  }
  #pragma unroll
  for (int i=0;i<16;i++){
    int idx = i*256+tid;
    int r = idx>>5, c4 = (idx&31)<<2;
    *(float4*)&Ws[r*132+c4] = *(const float4*)&W[r*DD + c4];
  }
  __syncthreads();
  int rg = tid>>4, cg = tid&15;
  int r0 = rg*2, c0 = cg*8;
  float acc[2][8];
  #pragma unroll
  for (int a=0;a<2;a++)
    #pragma unroll
    for (int b=0;b<8;b++) acc[a][b]=0.f;
  for (int kk=0;kk<128;kk+=4){
    float a0[4], a1[4];
    *(float4*)a0 = *(float4*)&As[r0*132+kk];
    *(float4*)a1 = *(float4*)&As[(r0+1)*132+kk];
    #pragma unroll
    for (int j=0;j<4;j++){
      float w[8];
      *(float4*)&w[0] = *(float4*)&Ws[(kk+j)*132+c0];
      *(float4*)&w[4] = *(float4*)&Ws[(kk+j)*132+c0+4];
      #pragma unroll
      for (int m=0;m<8;m++){
        acc[0][m] += a0[j]*w[m];
        acc[1][m] += a1[j]*w[m];
      }
    }
  }
  #pragma unroll
  for (int a=0;a<2;a++){
    int row = row0 + r0 + a;
    float val[8];
    #pragma unroll
    for (int m=0;m<8;m++) val[m] = acc[a][m] + bias[c0+m];
    if (mode == 2) {
      #pragma unroll
      for (int m=0;m<8;m++){
        int d = c0 + m;
        vT[(size_t)d*TT + (row ^ ((d&7)<<2))] = f2bf(val[m]);
      }
    } else {
      unsigned short h8[8], l8[8];
      #pragma unroll
      for (int m=0;m<8;m++){
        unsigned short hb = f2bf(val[m]);
        h8[m] = hb;
        l8[m] = f2bf(val[m] - bf2f(hb));
      }
      int dc = (mode == 1) ? 8*(cg ^ (row&7)) : c0;
      unsigned short* o1 = (mode==1) ? kh : qh;
      unsigned short* o2 = (mode==1) ? kl : ql;
      *(u16x8*)&o1[(size_t)row*DD + dc] = *(const u16x8*)h8;
      *(u16x8*)&o2[(size_t)row*DD + dc] = *(const u16x8*)l8;
    }
  }
}

// one wave per node; lane handles channels {lane, lane+64}
__global__ __launch_bounds__(256) void k_gather(const float* __restrict__ m, const float* __restrict__ bias,
                                                const float* __restrict__ norm, const int* __restrict__ offs,
                                                const int* __restrict__ csr, float* __restrict__ hout,
                                                int ldc) {
  int w = threadIdx.x>>6, lane = threadIdx.x&63;
  int t = blockIdx.x*4 + w;
  float nt = norm[t];
  float cs = nt*nt;
  float acc0 = m[t*DD + lane]*cs;
  float acc1 = m[t*DD + 64 + lane]*cs;
  int e0 = offs[t], e1 = offs[t+1];
  for (int e=e0;e<e1;e++){
    int s = csr[e];
    float cf = norm[s]*nt;
    acc0 += m[s*DD + lane]*cf;
    acc1 += m[s*DD + 64 + lane]*cf;
  }
  hout[(size_t)t*ldc + lane]      = tanhf(acc0 + bias[lane]);
  hout[(size_t)t*ldc + 64 + lane] = tanhf(acc1 + bias[64+lane]);
}

// W2 = Wo @ (Wc[:128]+Wc[128:]);  b2 = bo @ (Wc[:128]+Wc[128:]) + bc
__global__ __launch_bounds__(256) void k_w2(const float* __restrict__ Wo, const float* __restrict__ bo,
                                            const float* __restrict__ Wc, const float* __restrict__ bc,
                                            float* __restrict__ W2, float* __restrict__ b2) {
  if (blockIdx.x < 64) {
    int gid = blockIdx.x*256 + threadIdx.x;
    int i = gid>>7, j = gid&127;
    float s = 0.f;
    for (int k2=0;k2<128;k2++)
      s += Wo[i*DD+k2]*(Wc[k2*DD+j] + Wc[(k2+128)*DD+j]);
    W2[i*DD+j] = s;
  } else if (threadIdx.x < 128) {
    int j = threadIdx.x;
    float s = bc[j];
    for (int k2=0;k2<128;k2++)
      s += bo[k2]*(Wc[k2*DD+j] + Wc[(k2+128)*DD+j]);
    b2[j] = s;
  }
}

// MFMA flash attention, 512 threads = 8 waves = 2 groups of 4.
// Group h handles K-rows [32h,32h+32) of every 64-row tile (intra-block K-split);
// groups combine (m,l,O) through LDS at the end. Global KSPLIT=2 across blocks.
// 2 waves/SIMD -> MFMA of one wave overlaps VALU/LDS/barrier of the other.
__global__ __launch_bounds__(512) void k_flash_mfma(
    const unsigned short* __restrict__ qhg, const unsigned short* __restrict__ qlg,
    const unsigned short* __restrict__ khg, const unsigned short* __restrict__ klg,
    const unsigned short* __restrict__ vTg,
    float* __restrict__ Opart, float* __restrict__ pm, float* __restrict__ pl)
{
  __shared__ union {
    struct {
      unsigned short Kh[2][32*128];
      unsigned short Kl[2][32*128];
      unsigned short Vt[2][128*32];
    } s;
    float ex[12288];
  } u;
  const int tid  = threadIdx.x;
  const int lane = tid & 63;
  const int w8   = tid >> 6;     // 0..7
  const int h    = w8 >> 2;      // K-half group
  const int wq   = w8 & 3;       // q-sub wave within group
  const int l15  = lane & 15;
  const int g    = lane >> 4;
  const int qt   = blockIdx.x >> 1;
  const int sp   = blockIdx.x & 1;
  const int q0   = qt*64;

  // Q B-frags (hi/lo), 4 d-steps, in registers for the whole kernel
  bfrag qfh[4], qfl[4];
  {
    const unsigned short* qr  = qhg + (size_t)(q0 + 16*wq + l15)*DD + 8*g;
    const unsigned short* qr2 = qlg + (size_t)(q0 + 16*wq + l15)*DD + 8*g;
    #pragma unroll
    for (int ds=0; ds<4; ++ds){
      qfh[ds] = *(const bfrag*)(qr  + 32*ds);
      qfl[ds] = *(const bfrag*)(qr2 + 32*ds);
    }
  }
  float mrun = -1e30f, lrun = 0.f;
  ffrag o[8];
  #pragma unroll
  for (int nt=0;nt<8;++nt) o[nt] = (ffrag){0.f,0.f,0.f,0.f};

  unsigned short* Khb = u.s.Kh[h];
  unsigned short* Klb = u.s.Kl[h];
  unsigned short* Vtb = u.s.Vt[h];

  for (int tile=0; tile<64; ++tile){
    const size_t kb = (size_t)(sp*4096 + tile*64 + 32*h);
    __syncthreads();                       // previous tile's LDS reads done
    #pragma unroll
    for (int i=0;i<6;++i){
      const int cid = i*4 + wq;            // 0..23 per group
      const int j   = cid & 7;
      const int L   = 512*j + lane*8;
      if (cid < 8)       GLOAD16(khg + kb*DD + L, &Khb[512*j]);
      else if (cid < 16) GLOAD16(klg + kb*DD + L, &Klb[512*j]);
      else               GLOAD16(vTg + (size_t)(L>>5)*TT + kb + (L&31), &Vtb[512*j]);
    }
    __syncthreads();                       // staging complete

    // ---- S^T = K . Q^T (32 k-rows x 16 q), 3-term hi/lo split ----
    ffrag s[2];
    s[0] = (ffrag){0.f,0.f,0.f,0.f};
    s[1] = (ffrag){0.f,0.f,0.f,0.f};
    #pragma unroll
    for (int ds=0; ds<4; ++ds){
      const int koff = (32*ds + 8*g) ^ ((l15&7)<<3);
      #pragma unroll
      for (int mt=0; mt<2; ++mt){
        const int rb = (16*mt + l15)*DD + koff;
        bfrag ka = *(const bfrag*)&Khb[rb];
        bfrag kc = *(const bfrag*)&Klb[rb];
        s[mt] = MFMA(ka, qfh[ds], s[mt]);
        s[mt] = MFMA(kc, qfh[ds], s[mt]);
        s[mt] = MFMA(ka, qfl[ds], s[mt]);
      }
    }

    // ---- online softmax: lane holds 8 of this group's 32 k-values for q-col l15 ----
    float tmax = -1e30f;
    #pragma unroll
    for (int mt=0;mt<2;++mt)
      #pragma unroll
      for (int r=0;r<4;++r) tmax = fmaxf(tmax, s[mt][r]);
    tmax = fmaxf(tmax, __shfl_xor(tmax, 16));
    tmax = fmaxf(tmax, __shfl_xor(tmax, 32));
    const float mnew = fmaxf(mrun, tmax);
    float p[2][4];
    float psum = 0.f;
    #pragma unroll
    for (int mt=0;mt<2;++mt)
      #pragma unroll
      for (int r=0;r<4;++r){ float e = __expf(s[mt][r]-mnew); p[mt][r]=e; psum += e; }
    psum += __shfl_xor(psum, 16);
    psum += __shfl_xor(psum, 32);
    if (__any(mnew > mrun)) {
      const float scale = __expf(mrun - mnew);
      #pragma unroll
      for (int r=0;r<4;++r){
        const float sc = __shfl(scale, 4*g + r);
        #pragma unroll
        for (int nt=0;nt<8;++nt) o[nt][r] *= sc;
      }
      lrun = lrun*scale + psum;
      mrun = mnew;
    } else {
      lrun += psum;
    }

    // ---- PV: O += P.V over this group's 32 k ----
    bfrag pf;
    pf[0]=(short)f2bf(p[0][0]); pf[1]=(short)f2bf(p[0][1]);
    pf[2]=(short)f2bf(p[0][2]); pf[3]=(short)f2bf(p[0][3]);
    pf[4]=(short)f2bf(p[1][0]); pf[5]=(short)f2bf(p[1][1]);
    pf[6]=(short)f2bf(p[1][2]); pf[7]=(short)f2bf(p[1][3]);
    const int gr0 = g ^ (l15&7);
    const int gr1 = (4+g) ^ (l15&7);
    #pragma unroll
    for (int nt=0;nt<8;++nt){
      const unsigned short* vrow = &Vtb[(16*nt + l15)*32];
      bfrag4 va = *(const bfrag4*)(vrow + 4*gr0);
      bfrag4 vb = *(const bfrag4*)(vrow + 4*gr1);
      bfrag vf = __builtin_shufflevector(va, vb, 0,1,2,3,4,5,6,7);
      o[nt] = MFMA(pf, vf, o[nt]);
    }
  }

  // ---- inter-group combine via LDS, then epilogue ----
  __syncthreads();
  const int i2 = (wq<<6) | lane;          // 0..255 within group
  if (h==1){
    #pragma unroll
    for (int nt=0;nt<8;++nt)
      #pragma unroll
      for (int r=0;r<4;++r) u.ex[i2*33 + nt*4 + r] = o[nt][r];
    u.ex[8448 + i2] = mrun;
    u.ex[8704 + i2] = lrun;
  }
  __syncthreads();
  if (h==0){
    #pragma unroll
    for (int r=0;r<4;++r){
      const int q = 4*g + r;
      float m0q = __shfl(mrun, q);
      float m1q = u.ex[8448 + (wq<<6) + q];
      float mm  = fmaxf(m0q, m1q);
      float w0  = __expf(m0q - mm), w1 = __expf(m1q - mm);
      #pragma unroll
      for (int nt=0;nt<8;++nt)
        o[nt][r] = o[nt][r]*w0 + u.ex[i2*33 + nt*4 + r]*w1;
    }
    #pragma unroll
    for (int r=0;r<4;++r){
      float* dst = &Opart[((size_t)sp*TT + q0 + 16*wq + 4*g + r)*DD + l15];
      #pragma unroll
      for (int nt=0;nt<8;++nt) dst[16*nt] = o[nt][r];
    }
    if (g==0){
      float m1q = u.ex[8448 + (wq<<6) + l15];
      float l1q = u.ex[8704 + (wq<<6) + l15];
      float mm  = fmaxf(mrun, m1q);
      pm[sp*TT + q0 + 16*wq + l15] = mm;
      pl[sp*TT + q0 + 16*wq + l15] = lrun*__expf(mrun-mm) + l1q*__expf(m1q-mm);
    }
  }
}

// final GEMM with inline 2-split softmax combine on the A-load:
// A[t] = (Opart0[t]*w0 + Opart1[t]*w1)/den ; out[:,128:256] = A@W2 + b2
__global__ __launch_bounds__(256) void k_gemm_final(const float* __restrict__ Opart,
                                                    const float* __restrict__ pm, const float* __restrict__ pl,
                                                    const float* __restrict__ W2, const float* __restrict__ b2,
                                                    float* __restrict__ out) {
  __shared__ float As[32*132];
  __shared__ float Ws[128*132];
  int tid = threadIdx.x;
  int row0 = blockIdx.x*32;
  #pragma unroll
  for (int i=0;i<4;i++){
    int idx = i*256+tid;
    int r = idx>>5, c4 = (idx&31)<<2;
    int t = row0 + r;
    float m0 = pm[t], m1 = pm[TT+t];
    float mx = fmaxf(m0,m1);
    float w0 = __expf(m0-mx), w1 = __expf(m1-mx);
    float den = pl[t]*w0 + pl[TT+t]*w1;
    float u0 = w0/den, u1 = w1/den;
    float4 a = *(const float4*)&Opart[(size_t)t*DD + c4];
    float4 b = *(const float4*)&Opart[((size_t)TT + t)*DD + c4];
    float4 vv;
    vv.x = a.x*u0 + b.x*u1; vv.y = a.y*u0 + b.y*u1;
    vv.z = a.z*u0 + b.z*u1; vv.w = a.w*u0 + b.w*u1;
    *(float4*)&As[r*132+c4] = vv;
  }
  #pragma unroll
  for (int i=0;i<16;i++){
    int idx = i*256+tid;
    int r = idx>>5, c4 = (idx&31)<<2;
    *(float4*)&Ws[r*132+c4] = *(const float4*)&W2[r*DD + c4];
  }
  __syncthreads();
  int rg = tid>>4, cg = tid&15;
  int r0 = rg*2, c0 = cg*8;
  float acc[2][8];
  #pragma unroll
  for (int a=0;a<2;a++)
    #pragma unroll
    for (int b=0;b<8;b++) acc[a][b]=0.f;
  for (int kk=0;kk<128;kk+=4){
    float a0[4], a1[4];
    *(float4*)a0 = *(float4*)&As[r0*132+kk];
    *(float4*)a1 = *(float4*)&As[(r0+1)*132+kk];
    #pragma unroll
    for (int j=0;j<4;j++){
      float w[8];
      *(float4*)&w[0] = *(float4*)&Ws[(kk+j)*132+c0];
      *(float4*)&w[4] = *(float4*)&Ws[(kk+j)*132+c0+4];
      #pragma unroll
      for (int m=0;m<8;m++){
        acc[0][m] += a0[j]*w[m];
        acc[1][m] += a1[j]*w[m];
      }
    }
  }
  #pragma unroll
  for (int a=0;a<2;a++){
    float outv[8];
    #pragma unroll
    for (int m=0;m<8;m++) outv[m] = acc[a][m] + b2[c0+m];
    float* dst = &out[(size_t)(row0+r0+a)*(2*DD) + DD + c0];
    *(float4*)&dst[0] = *(float4*)&outv[0];
    *(float4*)&dst[4] = *(float4*)&outv[4];
  }
}

extern "C" void kernel_launch(void* const* d_in, const int* in_sizes, int n_in,
                              void* d_out, int out_size, void* d_ws, size_t ws_size,
                              hipStream_t stream) {
  const float* x  = (const float*)d_in[0];
  const int* edges = (const int*)d_in[1];
  const float* Wg = (const float*)d_in[2];
  const float* bg = (const float*)d_in[3];
  const float* Wq = (const float*)d_in[4];
  const float* bq = (const float*)d_in[5];
  const float* Wk = (const float*)d_in[6];
  const float* bk = (const float*)d_in[7];
  const float* Wv = (const float*)d_in[8];
  const float* bv = (const float*)d_in[9];
  const float* Wo = (const float*)d_in[10];
  const float* bo = (const float*)d_in[11];
  const float* Wc = (const float*)d_in[12];
  const float* bc = (const float*)d_in[13];
  float* out = (float*)d_out;
  char* ws = (char*)d_ws;

  int* count = (int*)(ws + WS_COUNT);
  int* fill  = (int*)(ws + WS_FILL);
  int* offs  = (int*)(ws + WS_OFFS);
  float* norm = (float*)(ws + WS_NORM);
  int* csr   = (int*)(ws + WS_CSR);
  float* W2  = (float*)(ws + WS_W2);
  float* b2  = (float*)(ws + WS_B2);
  float* pm  = (float*)(ws + WS_PM);
  float* pl  = (float*)(ws + WS_PL);
  float* h0  = (float*)(ws + WS_H0);
  float* h1  = (float*)(ws + WS_H1);
  float* mbuf = (float*)(ws + WS_M);
  float* Opart = (float*)(ws + WS_OPART);
  // bf16 buffers reuse the GCN scratch (GCN finishes before projections run)
  unsigned short* qhb = (unsigned short*)(ws + WS_H0);
  unsigned short* qlb = (unsigned short*)(ws + WS_H0 + (2u<<20));
  unsigned short* khb = (unsigned short*)(ws + WS_H1);
  unsigned short* klb = (unsigned short*)(ws + WS_H1 + (2u<<20));
  unsigned short* vTb = (unsigned short*)(ws + WS_M);

  // CSR build
  k_zero<<<64,256,0,stream>>>(count, 16384);
  k_count<<<NEDGE/256,256,0,stream>>>(edges, count);
  k_scan<<<1,1024,0,stream>>>(count, offs, norm);
  k_fill<<<NEDGE/256,256,0,stream>>>(edges, offs, fill, csr);

  // GCN: x -> h0 -> h1 -> h0 -> out[:, :128]
  const float* cur = x;
  float* hb[2] = {h0, h1};
  for (int l=0; l<4; ++l) {
    k_gemm<<<256,256,0,stream>>>(cur, Wg + l*DD*DD, nullptr, mbuf, DD, 0);
    float* nxt; int ldc;
    if (l < 3) { nxt = hb[l&1]; ldc = DD; } else { nxt = out; ldc = 2*DD; }
    k_gather<<<TT/4,256,0,stream>>>(mbuf, bg + l*DD, norm, offs, csr, nxt, ldc);
    cur = nxt;
  }

  // projections (merged QKV launch) + fused output weight
  k_proj3<<<768,256,0,stream>>>(x, Wq, bq, Wk, bk, Wv, bv, qhb, qlb, khb, klb, vTb);
  k_w2<<<65,256,0,stream>>>(Wo, bo, Wc, bc, W2, b2);

  k_flash_mfma<<<256,512,0,stream>>>(qhb, qlb, khb, klb, vTb, Opart, pm, pl);
  k_gemm_final<<<256,256,0,stream>>>(Opart, pm, pl, W2, b2, out);
}

// Round 4
// 262.747 us; speedup vs baseline: 3.3976x; 1.1325x over previous
//
#include <hip/hip_runtime.h>
#include <math.h>

#define TT 8192
#define DD 128
#define GB 64
#define GN 128
#define GE 2048
#define NEDGE (GB*GE)   // 131072

// ---- workspace layout (bytes) ----
#define WS_COUNT   0u            // 8192 int
#define WS_FILL    (32u<<10)     // 8192 int
#define WS_OFFS    (64u<<10)     // 8193 int
#define WS_NORM    (100u<<10)    // 8192 f32
#define WS_CSR     (132u<<10)    // 131072 int
#define WS_W2      (644u<<10)    // 128*128 f32
#define WS_B2      (708u<<10)    // 128 f32
#define WS_PM      (709u<<10)    // 2*8192 f32
#define WS_PL      (773u<<10)    // 2*8192 f32
#define WS_H0      (1u<<20)      // 4MB region: GCN h0; later q16 (2MB)
#define WS_H1      (5u<<20)      // 4MB region: GCN h1; later k16 frag-order (2MB)
#define WS_M       (9u<<20)      // 4MB region: GCN mbuf; later vT frag-order (2MB)
#define WS_OPART   (13u<<20)     // 8MB
// total 21MB

typedef _Float16 hfrag  __attribute__((ext_vector_type(8)));
typedef float    ffrag  __attribute__((ext_vector_type(4)));

#define MFMA16(a,b,c) __builtin_amdgcn_mfma_f32_16x16x32_f16((a),(b),(c),0,0,0)

typedef __attribute__((address_space(1))) unsigned int gu32_t;
typedef __attribute__((address_space(3))) unsigned int lu32_t;
#define GLOAD16(gp, lp) __builtin_amdgcn_global_load_lds((gu32_t*)(const void*)(gp), (lu32_t*)(void*)(lp), 16, 0, 0)

__global__ __launch_bounds__(256) void k_zero(int* __restrict__ p, int n) {
  int i = blockIdx.x*256 + threadIdx.x;
  if (i < n) p[i] = 0;
}

__global__ __launch_bounds__(256) void k_count(const int* __restrict__ edges, int* __restrict__ count) {
  int e = blockIdx.x*256 + threadIdx.x;
  int b = e >> 11;
  int i = e & 2047;
  int dst = edges[b*2*GE + GE + i] + b*GN;
  atomicAdd(&count[dst], 1);
}

__global__ __launch_bounds__(1024) void k_scan(const int* __restrict__ count, int* __restrict__ offs,
                                               float* __restrict__ norm) {
  __shared__ int lds[1024];
  int tid = threadIdx.x;
  int base = tid*8;
  int loc[8]; int tot = 0;
  #pragma unroll
  for (int j=0;j<8;j++){ loc[j]=count[base+j]; tot+=loc[j]; }
  lds[tid]=tot; __syncthreads();
  for (int s=1;s<1024;s<<=1){
    int v = (tid>=s)? lds[tid-s] : 0;
    __syncthreads();
    lds[tid]+=v;
    __syncthreads();
  }
  int ex = lds[tid]-tot;
  #pragma unroll
  for (int j=0;j<8;j++){
    offs[base+j]=ex; ex+=loc[j];
    norm[base+j]=rsqrtf(1.0f+(float)loc[j]);
  }
  if (tid==1023) offs[TT]=ex;
}

__global__ __launch_bounds__(256) void k_fill(const int* __restrict__ edges, const int* __restrict__ offs,
                                              int* __restrict__ fill, int* __restrict__ csr) {
  int e = blockIdx.x*256+threadIdx.x;
  int b = e>>11, i = e&2047;
  int s = edges[b*2*GE + i] + b*GN;
  int d = edges[b*2*GE + GE + i] + b*GN;
  int pos = offs[d] + atomicAdd(&fill[d],1);
  csr[pos] = s;
}

// C[M,128] = A[M,128] @ W[128,128] (+bias), written at C[row*ldc + cofs + col]
__global__ __launch_bounds__(256) void k_gemm(const float* __restrict__ A, const float* __restrict__ W,
                                              const float* __restrict__ bias, float* __restrict__ C,
                                              int ldc, int cofs) {
  __shared__ float As[32*132];
  __shared__ float Ws[128*132];
  int tid = threadIdx.x;
  int row0 = blockIdx.x*32;
  #pragma unroll
  for (int i=0;i<4;i++){
    int idx = i*256+tid;
    int r = idx>>5, c4 = (idx&31)<<2;
    *(float4*)&As[r*132+c4] = *(const float4*)&A[(row0+r)*DD + c4];
  }
  #pragma unroll
  for (int i=0;i<16;i++){
    int idx = i*256+tid;
    int r = idx>>5, c4 = (idx&31)<<2;
    *(float4*)&Ws[r*132+c4] = *(const float4*)&W[r*DD + c4];
  }
  __syncthreads();
  int rg = tid>>4, cg = tid&15;
  int r0 = rg*2, c0 = cg*8;
  float acc[2][8];
  #pragma unroll
  for (int a=0;a<2;a++)
    #pragma unroll
    for (int b=0;b<8;b++) acc[a][b]=0.f;
  for (int kk=0;kk<128;kk+=4){
    float a0[4], a1[4];
    *(float4*)a0 = *(float4*)&As[r0*132+kk];
    *(float4*)a1 = *(float4*)&As[(r0+1)*132+kk];
    #pragma unroll
    for (int j=0;j<4;j++){
      float w[8];
      *(float4*)&w[0] = *(float4*)&Ws[(kk+j)*132+c0];
      *(float4*)&w[4] = *(float4*)&Ws[(kk+j)*132+c0+4];
      #pragma unroll
      for (int m=0;m<8;m++){
        acc[0][m] += a0[j]*w[m];
        acc[1][m] += a1[j]*w[m];
      }
    }
  }
  #pragma unroll
  for (int a=0;a<2;a++){
    float outv[8];
    #pragma unroll
    for (int m=0;m<8;m++)
      outv[m] = acc[a][m] + (bias ? bias[c0+m] : 0.f);
    float* dst = &C[(size_t)(row0+r0+a)*ldc + cofs + c0];
    *(float4*)&dst[0] = *(float4*)&outv[0];
    *(float4*)&dst[4] = *(float4*)&outv[4];
  }
}

// merged Q/K/V projections -> f16, one launch, grid 768.
// mode 0 (Q): q16[row][d]                              (plain)
// mode 1 (K): fragment-order: frag (R=row/16, ds=d/32): elem ((R*4+ds)*64 + (row&15) + 16*g)*8 + j
//             where g=(d>>3)&3, j=d&7  -> linear LDS staging gives conflict-free b128 A-frag reads
// mode 2 (V): V^T fragment-order with PV k-permutation kappa(g,j)=(j>>2)*16+4g+(j&3):
//             elem ((C*8 + nt)*64 + (d&15) + 16*g)*8 + j, C=row/32, nt=d/16,
//             g=(kloc&15)>>2, j=((kloc>>4)<<2)|(kloc&3), kloc=row&31
__global__ __launch_bounds__(256) void k_proj3(const float* __restrict__ A,
                                               const float* __restrict__ Wq, const float* __restrict__ bq_,
                                               const float* __restrict__ Wk, const float* __restrict__ bk_,
                                               const float* __restrict__ Wv, const float* __restrict__ bv_,
                                               _Float16* __restrict__ q16,
                                               _Float16* __restrict__ k16,
                                               _Float16* __restrict__ vT) {
  __shared__ float As[32*132];
  __shared__ float Ws[128*132];
  const int mode = blockIdx.x >> 8;
  const int row0 = (blockIdx.x & 255) * 32;
  const float* W    = (mode==0) ? Wq : (mode==1) ? Wk : Wv;
  const float* bias = (mode==0) ? bq_ : (mode==1) ? bk_ : bv_;
  int tid = threadIdx.x;
  #pragma unroll
  for (int i=0;i<4;i++){
    int idx = i*256+tid;
    int r = idx>>5, c4 = (idx&31)<<2;
    *(float4*)&As[r*132+c4] = *(const float4*)&A[(row0+r)*DD + c4];
  }
  #pragma unroll
  for (int i=0;i<16;i++){
    int idx = i*256+tid;
    int r = idx>>5, c4 = (idx&31)<<2;
    *(float4*)&Ws[r*132+c4] = *(const float4*)&W[r*DD + c4];
  }
  __syncthreads();
  int rg = tid>>4, cg = tid&15;
  int r0 = rg*2, c0 = cg*8;
  float acc[2][8];
  #pragma unroll
  for (int a=0;a<2;a++)
    #pragma unroll
    for (int b=0;b<8;b++) acc[a][b]=0.f;
  for (int kk=0;kk<128;kk+=4){
    float a0[4], a1[4];
    *(float4*)a0 = *(float4*)&As[r0*132+kk];
    *(float4*)a1 = *(float4*)&As[(r0+1)*132+kk];
    #pragma unroll
    for (int j=0;j<4;j++){
      float w[8];
      *(float4*)&w[0] = *(float4*)&Ws[(kk+j)*132+c0];
      *(float4*)&w[4] = *(float4*)&Ws[(kk+j)*132+c0+4];
      #pragma unroll
      for (int m=0;m<8;m++){
        acc[0][m] += a0[j]*w[m];
        acc[1][m] += a1[j]*w[m];
      }
    }
  }
  #pragma unroll
  for (int a=0;a<2;a++){
    int row = row0 + r0 + a;
    float val[8];
    #pragma unroll
    for (int m=0;m<8;m++) val[m] = acc[a][m] + bias[c0+m];
    if (mode == 0) {
      hfrag t;
      #pragma unroll
      for (int m=0;m<8;m++) t[m] = (_Float16)val[m];
      *(hfrag*)&q16[(size_t)row*DD + c0] = t;
    } else if (mode == 1) {
      hfrag t;
      #pragma unroll
      for (int m=0;m<8;m++) t[m] = (_Float16)val[m];
      int R = row>>4, l15r = row&15, dsx = cg>>2, gx = cg&3;
      *(hfrag*)&k16[((size_t)(R*4+dsx)*64 + l15r + 16*gx)*8] = t;
    } else {
      int C = row>>5, kloc = row&31;
      int gx = (kloc&15)>>2;
      int jx = ((kloc>>4)<<2) | (kloc&3);
      #pragma unroll
      for (int m=0;m<8;m++){
        int d = c0+m;
        vT[((size_t)(C*8 + (d>>4))*64 + (d&15) + 16*gx)*8 + jx] = (_Float16)val[m];
      }
    }
  }
}

// one wave per node; lane handles channels {lane, lane+64}
__global__ __launch_bounds__(256) void k_gather(const float* __restrict__ m, const float* __restrict__ bias,
                                                const float* __restrict__ norm, const int* __restrict__ offs,
                                                const int* __restrict__ csr, float* __restrict__ hout,
                                                int ldc) {
  int w = threadIdx.x>>6, lane = threadIdx.x&63;
  int t = blockIdx.x*4 + w;
  float nt = norm[t];
  float cs = nt*nt;
  float acc0 = m[t*DD + lane]*cs;
  float acc1 = m[t*DD + 64 + lane]*cs;
  int e0 = offs[t], e1 = offs[t+1];
  for (int e=e0;e<e1;e++){
    int s = csr[e];
    float cf = norm[s]*nt;
    acc0 += m[s*DD + lane]*cf;
    acc1 += m[s*DD + 64 + lane]*cf;
  }
  hout[(size_t)t*ldc + lane]      = tanhf(acc0 + bias[lane]);
  hout[(size_t)t*ldc + 64 + lane] = tanhf(acc1 + bias[64+lane]);
}

// W2 = Wo @ (Wc[:128]+Wc[128:]);  b2 = bo @ (Wc[:128]+Wc[128:]) + bc
__global__ __launch_bounds__(256) void k_w2(const float* __restrict__ Wo, const float* __restrict__ bo,
                                            const float* __restrict__ Wc, const float* __restrict__ bc,
                                            float* __restrict__ W2, float* __restrict__ b2) {
  if (blockIdx.x < 64) {
    int gid = blockIdx.x*256 + threadIdx.x;
    int i = gid>>7, j = gid&127;
    float s = 0.f;
    for (int k2=0;k2<128;k2++)
      s += Wo[i*DD+k2]*(Wc[k2*DD+j] + Wc[(k2+128)*DD+j]);
    W2[i*DD+j] = s;
  } else if (threadIdx.x < 128) {
    int j = threadIdx.x;
    float s = bc[j];
    for (int k2=0;k2<128;k2++)
      s += bo[k2]*(Wc[k2*DD+j] + Wc[(k2+128)*DD+j]);
    b2[j] = s;
  }
}

// Read-once MFMA flash attention.
// 256 threads = 4 waves. Block: 64 q-cols x 4096 k (KSPLIT=2). Tile = 256 k-rows.
// Wave w owns k-rows [64w,64w+64) of every tile with its own online (m,l,O);
// 4-way merge in LDS at the end. All operands f16 in fragment order so every
// LDS access is a lane-contiguous ds_read_b128 (conflict-free) and every K/V
// byte is read by exactly one wave. Counted vmcnt: QK overlaps V staging.
__global__ __launch_bounds__(256,1) void k_flash2(
    const _Float16* __restrict__ q16, const _Float16* __restrict__ k16f,
    const _Float16* __restrict__ vTf,
    float* __restrict__ Opart, float* __restrict__ pm, float* __restrict__ pl)
{
  __shared__ union {
    struct { _Float16 K[32768]; _Float16 V[32768]; } s;   // 64KB + 64KB
    struct { float O[2][8192]; float ml[512]; } c;        // 4-wave combine scratch
  } u;
  const int tid  = threadIdx.x;
  const int lane = tid & 63;
  const int w    = tid >> 6;          // k-slice owner (0..3)
  const int l15  = lane & 15;
  const int g    = lane >> 4;
  const int q0   = (blockIdx.x >> 1) * 64;
  const int sp   = blockIdx.x & 1;

  // Q B-frags [qb][ds] in registers for the whole kernel (same 64 q for all waves)
  hfrag qf[4][4];
  #pragma unroll
  for (int qb=0;qb<4;++qb)
    #pragma unroll
    for (int ds=0;ds<4;++ds)
      qf[qb][ds] = *(const hfrag*)&q16[(size_t)(q0+16*qb+l15)*DD + 32*ds + 8*g];

  float mrun[4], lrun[4];
  ffrag o[4][8];
  #pragma unroll
  for (int qb=0;qb<4;++qb){
    mrun[qb] = -1e30f; lrun[qb] = 0.f;
    #pragma unroll
    for (int nt=0;nt<8;++nt) o[qb][nt] = (ffrag){0.f,0.f,0.f,0.f};
  }

  for (int t=0; t<16; ++t){
    __builtin_amdgcn_s_barrier();                 // prev tile's LDS reads done
    const _Float16* Ksrc = k16f + (size_t)(sp*4096 + 256*t)*DD;
    const _Float16* Vsrc = vTf  + (size_t)(sp*4096 + 256*t)*DD;
    #pragma unroll
    for (int i=0;i<16;++i){
      const int base = i*2048 + w*512;
      GLOAD16(Ksrc + base + lane*8, &u.s.K[base]);
    }
    #pragma unroll
    for (int i=0;i<16;++i){
      const int base = i*2048 + w*512;
      GLOAD16(Vsrc + base + lane*8, &u.s.V[base]);
    }
    asm volatile("s_waitcnt vmcnt(16)" ::: "memory");   // K landed (V still in flight)
    __builtin_amdgcn_s_barrier();

    // ---- S^T = K . Q^T over this wave's 64 k-rows ----
    ffrag s[4][4];   // [qb][mt]
    #pragma unroll
    for (int qb=0;qb<4;++qb)
      #pragma unroll
      for (int mt=0;mt<4;++mt) s[qb][mt] = (ffrag){0.f,0.f,0.f,0.f};
    #pragma unroll
    for (int mt=0;mt<4;++mt)
      #pragma unroll
      for (int ds=0;ds<4;++ds){
        hfrag ka = *(const hfrag*)&u.s.K[((size_t)((4*w+mt)*4+ds))*512 + lane*8];
        #pragma unroll
        for (int qb=0;qb<4;++qb)
          s[qb][mt] = MFMA16(ka, qf[qb][ds], s[qb][mt]);
      }

    asm volatile("s_waitcnt vmcnt(0)" ::: "memory");    // V landed
    __builtin_amdgcn_s_barrier();

    // ---- online softmax (per-wave independent over its k-slice) ----
    #pragma unroll
    for (int qb=0;qb<4;++qb){
      float tmax = -1e30f;
      #pragma unroll
      for (int mt=0;mt<4;++mt)
        tmax = fmaxf(tmax, fmaxf(fmaxf(s[qb][mt][0], s[qb][mt][1]),
                                 fmaxf(s[qb][mt][2], s[qb][mt][3])));
      tmax = fmaxf(tmax, __shfl_xor(tmax,16));
      tmax = fmaxf(tmax, __shfl_xor(tmax,32));
      const float mnew = fmaxf(mrun[qb], tmax);
      float psum = 0.f;
      #pragma unroll
      for (int mt=0;mt<4;++mt)
        #pragma unroll
        for (int r=0;r<4;++r){ float e = __expf(s[qb][mt][r]-mnew); s[qb][mt][r]=e; psum += e; }
      psum += __shfl_xor(psum,16);
      psum += __shfl_xor(psum,32);
      if (__any(mnew > mrun[qb])){
        const float sc = __expf(mrun[qb]-mnew);
        lrun[qb] = lrun[qb]*sc + psum;
        mrun[qb] = mnew;
        #pragma unroll
        for (int r=0;r<4;++r){
          const float scr = __shfl(sc, 4*g+r);
          #pragma unroll
          for (int nt=0;nt<8;++nt) o[qb][nt][r] *= scr;
        }
      } else {
        lrun[qb] += psum;
      }
    }

    // ---- PV: O += P.V over the wave's two 32-k chunks ----
    #pragma unroll
    for (int c2=0;c2<2;++c2){
      hfrag pf[4];
      #pragma unroll
      for (int qb=0;qb<4;++qb)
        #pragma unroll
        for (int j=0;j<8;++j) pf[qb][j] = (_Float16)s[qb][2*c2+(j>>2)][j&3];
      #pragma unroll
      for (int nt=0;nt<8;++nt){
        hfrag vf = *(const hfrag*)&u.s.V[((size_t)((2*w+c2)*8+nt))*512 + lane*8];
        #pragma unroll
        for (int qb=0;qb<4;++qb)
          o[qb][nt] = MFMA16(pf[qb], vf, o[qb][nt]);
      }
    }
  }

  // ---- 4-wave merge (pairs (0,2),(1,3) then (0,1)), then global write ----
  __syncthreads();
  if (w >= 2){
    const int ws = w-2;
    #pragma unroll
    for (int qb=0;qb<4;++qb){
      #pragma unroll
      for (int r=0;r<4;++r){
        const int q = 16*qb + 4*g + r;
        #pragma unroll
        for (int nt=0;nt<8;++nt)
          u.c.O[ws][q*128 + 16*nt + l15] = o[qb][nt][r];
      }
      if (g==0){
        u.c.ml[ws*128 + 16*qb + l15]       = mrun[qb];
        u.c.ml[256 + ws*128 + 16*qb + l15] = lrun[qb];
      }
    }
  }
  __syncthreads();
  if (w < 2){
    #pragma unroll
    for (int qb=0;qb<4;++qb){
      float mo  = u.c.ml[w*128 + 16*qb + l15];
      float lo_ = u.c.ml[256 + w*128 + 16*qb + l15];
      float mn  = fmaxf(mrun[qb], mo);
      float a_  = __expf(mrun[qb]-mn);
      float b_  = __expf(mo-mn);
      lrun[qb] = lrun[qb]*a_ + lo_*b_;
      mrun[qb] = mn;
      #pragma unroll
      for (int r=0;r<4;++r){
        float aa = __shfl(a_, 4*g+r);
        float bb = __shfl(b_, 4*g+r);
        const int q = 16*qb + 4*g + r;
        #pragma unroll
        for (int nt=0;nt<8;++nt)
          o[qb][nt][r] = o[qb][nt][r]*aa + u.c.O[w][q*128 + 16*nt + l15]*bb;
      }
    }
  }
  __syncthreads();
  if (w == 1){
    #pragma unroll
    for (int qb=0;qb<4;++qb){
      #pragma unroll
      for (int r=0;r<4;++r){
        const int q = 16*qb + 4*g + r;
        #pragma unroll
        for (int nt=0;nt<8;++nt)
          u.c.O[0][q*128 + 16*nt + l15] = o[qb][nt][r];
      }
      if (g==0){
        u.c.ml[16*qb + l15]       = mrun[qb];
        u.c.ml[256 + 16*qb + l15] = lrun[qb];
      }
    }
  }
  __syncthreads();
  if (w == 0){
    #pragma unroll
    for (int qb=0;qb<4;++qb){
      float mo  = u.c.ml[16*qb + l15];
      float lo_ = u.c.ml[256 + 16*qb + l15];
      float mn  = fmaxf(mrun[qb], mo);
      float a_  = __expf(mrun[qb]-mn);
      float b_  = __expf(mo-mn);
      float lfin = lrun[qb]*a_ + lo_*b_;
      #pragma unroll
      for (int r=0;r<4;++r){
        float aa = __shfl(a_, 4*g+r);
        float bb = __shfl(b_, 4*g+r);
        const int q = 16*qb + 4*g + r;
        float* dst = &Opart[((size_t)sp*TT + q0 + q)*DD];
        #pragma unroll
        for (int nt=0;nt<8;++nt)
          dst[16*nt + l15] = o[qb][nt][r]*aa + u.c.O[0][q*128 + 16*nt + l15]*bb;
      }
      if (g==0){
        pm[sp*TT + q0 + 16*qb + l15] = mn;
        pl[sp*TT + q0 + 16*qb + l15] = lfin;
      }
    }
  }
}

// final GEMM with inline 2-split softmax combine on the A-load:
// A[t] = (Opart0[t]*w0 + Opart1[t]*w1)/den ; out[:,128:256] = A@W2 + b2
__global__ __launch_bounds__(256) void k_gemm_final(const float* __restrict__ Opart,
                                                    const float* __restrict__ pm, const float* __restrict__ pl,
                                                    const float* __restrict__ W2, const float* __restrict__ b2,
                                                    float* __restrict__ out) {
  __shared__ float As[32*132];
  __shared__ float Ws[128*132];
  int tid = threadIdx.x;
  int row0 = blockIdx.x*32;
  #pragma unroll
  for (int i=0;i<4;i++){
    int idx = i*256+tid;
    int r = idx>>5, c4 = (idx&31)<<2;
    int t = row0 + r;
    float m0 = pm[t], m1 = pm[TT+t];
    float mx = fmaxf(m0,m1);
    float w0 = __expf(m0-mx), w1 = __expf(m1-mx);
    float den = pl[t]*w0 + pl[TT+t]*w1;
    float u0 = w0/den, u1 = w1/den;
    float4 a = *(const float4*)&Opart[(size_t)t*DD + c4];
    float4 b = *(const float4*)&Opart[((size_t)TT + t)*DD + c4];
    float4 vv;
    vv.x = a.x*u0 + b.x*u1; vv.y = a.y*u0 + b.y*u1;
    vv.z = a.z*u0 + b.z*u1; vv.w = a.w*u0 + b.w*u1;
    *(float4*)&As[r*132+c4] = vv;
  }
  #pragma unroll
  for (int i=0;i<16;i++){
    int idx = i*256+tid;
    int r = idx>>5, c4 = (idx&31)<<2;
    *(float4*)&Ws[r*132+c4] = *(const float4*)&W2[r*DD + c4];
  }
  __syncthreads();
  int rg = tid>>4, cg = tid&15;
  int r0 = rg*2, c0 = cg*8;
  float acc[2][8];
  #pragma unroll
  for (int a=0;a<2;a++)
    #pragma unroll
    for (int b=0;b<8;b++) acc[a][b]=0.f;
  for (int kk=0;kk<128;kk+=4){
    float a0[4], a1[4];
    *(float4*)a0 = *(float4*)&As[r0*132+kk];
    *(float4*)a1 = *(float4*)&As[(r0+1)*132+kk];
    #pragma unroll
    for (int j=0;j<4;j++){
      float w[8];
      *(float4*)&w[0] = *(float4*)&Ws[(kk+j)*132+c0];
      *(float4*)&w[4] = *(float4*)&Ws[(kk+j)*132+c0+4];
      #pragma unroll
      for (int m=0;m<8;m++){
        acc[0][m] += a0[j]*w[m];
        acc[1][m] += a1[j]*w[m];
      }
    }
  }
  #pragma unroll
  for (int a=0;a<2;a++){
    float outv[8];
    #pragma unroll
    for (int m=0;m<8;m++) outv[m] = acc[a][m] + b2[c0+m];
    float* dst = &out[(size_t)(row0+r0+a)*(2*DD) + DD + c0];
    *(float4*)&dst[0] = *(float4*)&outv[0];
    *(float4*)&dst[4] = *(float4*)&outv[4];
  }
}

extern "C" void kernel_launch(void* const* d_in, const int* in_sizes, int n_in,
                              void* d_out, int out_size, void* d_ws, size_t ws_size,
                              hipStream_t stream) {
  const float* x  = (const float*)d_in[0];
  const int* edges = (const int*)d_in[1];
  const float* Wg = (const float*)d_in[2];
  const float* bg = (const float*)d_in[3];
  const float* Wq = (const float*)d_in[4];
  const float* bq = (const float*)d_in[5];
  const float* Wk = (const float*)d_in[6];
  const float* bk = (const float*)d_in[7];
  const float* Wv = (const float*)d_in[8];
  const float* bv = (const float*)d_in[9];
  const float* Wo = (const float*)d_in[10];
  const float* bo = (const float*)d_in[11];
  const float* Wc = (const float*)d_in[12];
  const float* bc = (const float*)d_in[13];
  float* out = (float*)d_out;
  char* ws = (char*)d_ws;

  int* count = (int*)(ws + WS_COUNT);
  int* fill  = (int*)(ws + WS_FILL);
  int* offs  = (int*)(ws + WS_OFFS);
  float* norm = (float*)(ws + WS_NORM);
  int* csr   = (int*)(ws + WS_CSR);
  float* W2  = (float*)(ws + WS_W2);
  float* b2  = (float*)(ws + WS_B2);
  float* pm  = (float*)(ws + WS_PM);
  float* pl  = (float*)(ws + WS_PL);
  float* h0  = (float*)(ws + WS_H0);
  float* h1  = (float*)(ws + WS_H1);
  float* mbuf = (float*)(ws + WS_M);
  float* Opart = (float*)(ws + WS_OPART);
  // f16 buffers reuse the GCN scratch (GCN finishes before projections run)
  _Float16* q16 = (_Float16*)(ws + WS_H0);
  _Float16* k16 = (_Float16*)(ws + WS_H1);
  _Float16* vT  = (_Float16*)(ws + WS_M);

  // CSR build
  k_zero<<<64,256,0,stream>>>(count, 16384);
  k_count<<<NEDGE/256,256,0,stream>>>(edges, count);
  k_scan<<<1,1024,0,stream>>>(count, offs, norm);
  k_fill<<<NEDGE/256,256,0,stream>>>(edges, offs, fill, csr);

  // GCN: x -> h0 -> h1 -> h0 -> out[:, :128]
  const float* cur = x;
  float* hb[2] = {h0, h1};
  for (int l=0; l<4; ++l) {
    k_gemm<<<256,256,0,stream>>>(cur, Wg + l*DD*DD, nullptr, mbuf, DD, 0);
    float* nxt; int ldc;
    if (l < 3) { nxt = hb[l&1]; ldc = DD; } else { nxt = out; ldc = 2*DD; }
    k_gather<<<TT/4,256,0,stream>>>(mbuf, bg + l*DD, norm, offs, csr, nxt, ldc);
    cur = nxt;
  }

  // projections (merged QKV launch, f16 fragment-order outputs) + fused output weight
  k_proj3<<<768,256,0,stream>>>(x, Wq, bq, Wk, bk, Wv, bv, q16, k16, vT);
  k_w2<<<65,256,0,stream>>>(Wo, bo, Wc, bc, W2, b2);

  k_flash2<<<256,256,0,stream>>>(q16, k16, vT, Opart, pm, pl);
  k_gemm_final<<<256,256,0,stream>>>(Opart, pm, pl, W2, b2, out);
}